// Round 9
// baseline (33.696 us; speedup 1.0000x reference)
//
#include <hip/hip_runtime.h>

#define NQ 12
#define NL 4
#define NT 512
// One batch element per block, 8 waves.
// storage position bits: 11,10,9 = wave id (wv bits 2,1,0); 8..3 = lane bits 5..0; 2..0 = slot
// per lane: 8 amps as 4 f32x2 (slot bit0 = f32x2 component)
// Per-phase layout sigma_t maps logical state bits -> storage positions. Gates on the 3
// wave-position bits of layer t are DEFERRED past the ring scatter into phase t+1, where
// (by construction of sigma_{t+1}) their pairing masks are lane/slot-local.

typedef float f32x2 __attribute__((ext_vector_type(2)));

// ---------------- constexpr GF(2) circuit algebra ----------------
constexpr unsigned gmap_f(int l, unsigned v) {      // gather map (verified r1)
    int r = l + 1; unsigned x = v;
    for (int q = NQ - 1; q >= 0; --q) {
        int cb = NQ - 1 - q, tw = (q + r) % NQ, tb = NQ - 1 - tw;
        x ^= ((x >> cb) & 1u) << tb;
    }
    return x;
}
constexpr unsigned ginv_f(int l, unsigned v) {      // scatter map (verified r5)
    int r = l + 1; unsigned x = v;
    for (int q = 0; q < NQ; ++q) {
        int cb = NQ - 1 - q, tw = (q + r) % NQ, tb = NQ - 1 - tw;
        x ^= ((x >> cb) & 1u) << tb;
    }
    return x;
}
constexpr unsigned phi_f(unsigned x) { return x ^ ((x >> 4) & 14u) ^ ((x >> 8) & 14u); }

// sigma_t: logical bit -> storage position (hand-derived; D_t bits at wave positions)
constexpr int POS[5][12] = {
    {0,1,2,3,4,5,6,7,8,9,10,11},        // sigma_0 = identity (phase 0)
    {9,10,11,0,1,2,3,4,5,6,7,8},        // sigma_1: D1={0,1,2}
    {0,1,2,9,5,6,10,7,8,11,3,4},        // sigma_2: D2={3,6,9}
    {0,4,5,1,6,7,2,8,9,3,10,11},        // sigma_3: D3={8,10,11}
    {0,9,2,4,1,10,3,5,11,6,7,8},        // sigma_4: D4={1,5,8}
};
constexpr int DBITS[3][3] = { {0,1,2}, {3,6,9}, {8,10,11} };   // D1,D2,D3

constexpr unsigned pv(int t, unsigned v) { unsigned r = 0; for (int b = 0; b < 12; ++b) if ((v >> b) & 1) r |= 1u << POS[t][b]; return r; }
constexpr int bitat(int t, int i) { for (int b = 0; b < 12; ++b) if (POS[t][b] == i) return b; return -1; }
constexpr unsigned rowmask(int l, int b) { unsigned r = 0; for (int j = 0; j < 12; ++j) if ((gmap_f(l, 1u << j) >> b) & 1) r |= 1u << j; return r; }

struct Tabs {
    unsigned lcol[4][9];    // scatter phases 0..3: byte cols for position bits 3..11
    unsigned scol[4][8];    // scatter byte combos over slot bits 0..2
    int      gq[4][9];      // current-gate matrix index at position i (phases 0..3)
    unsigned dm[3][3];      // deferred masks (applied in phases 2,3,4)
    unsigned dr[3][3];      // deferred parity rows (storage space)
    int      dg[3][3];      // deferred gate matrix index
    unsigned rfin[12];      // measurement masks (single storage bits)
};
constexpr Tabs make_tabs() {
    Tabs T{};
    for (int t = 0; t <= 3; ++t) {
        for (int i = 3; i < 12; ++i)
            T.lcol[t][i - 3] = phi_f(pv(t + 1, ginv_f(t, 1u << bitat(t, i)))) << 3;
        for (int s = 0; s < 8; ++s) {
            unsigned v = 0;
            for (int bp = 0; bp < 3; ++bp)
                if ((s >> bp) & 1) v ^= phi_f(pv(t + 1, ginv_f(t, 1u << bitat(t, bp)))) << 3;
            T.scol[t][s] = v;
        }
        for (int i = 0; i < 9; ++i)
            T.gq[t][i] = t * NQ + (11 - bitat(t, i));
    }
    for (int t = 2; t <= 4; ++t)
        for (int j = 0; j < 3; ++j) {
            const int b = DBITS[t - 2][j];
            T.dm[t - 2][j] = pv(t, ginv_f(t - 1, 1u << b));
            T.dr[t - 2][j] = pv(t, rowmask(t - 1, b));
            T.dg[t - 2][j] = (t - 1) * NQ + (11 - b);
        }
    for (int q = 0; q < 12; ++q) T.rfin[q] = 1u << POS[4][11 - q];
    return T;
}
constexpr Tabs CT = make_tabs();

constexpr bool chk() {
    for (int t = 1; t <= 4; ++t) { unsigned seen = 0; for (int b = 0; b < 12; ++b) seen |= 1u << POS[t][b]; if (seen != 0xFFFu) return false; }
    for (int t = 1; t <= 3; ++t)
        for (int j = 0; j < 3; ++j) {
            if (POS[t][DBITS[t - 1][j]] < 9) return false;                 // D_t at wave under sigma_t
            if (pv(t + 1, ginv_f(t, 1u << DBITS[t - 1][j])) >> 9) return false; // deferred mask lane/slot
        }
    for (int j = 0; j < 3; ++j) if ((CT.dm[0][j] >> 3) > 31 || (CT.dm[1][j] >> 3) > 31 || (CT.dm[2][j] >> 3) > 31) return false;
    return true;
}
static_assert(chk(), "layout constraints violated");

// ---------------- packed fp32 helpers (VOP3P) ----------------
__device__ __forceinline__ f32x2 pkmul(f32x2 a, f32x2 b) {
    f32x2 d; asm("v_pk_mul_f32 %0, %1, %2" : "=v"(d) : "v"(a), "v"(b)); return d;
}
__device__ __forceinline__ f32x2 pkfma(f32x2 a, f32x2 b, f32x2 c) {
    f32x2 d; asm("v_pk_fma_f32 %0, %1, %2, %3" : "=v"(d) : "v"(a), "v"(b), "v"(c)); return d;
}
__device__ __forceinline__ f32x2 pkfnma(f32x2 a, f32x2 b, f32x2 c) {   // c - a*b
    f32x2 d; asm("v_pk_fma_f32 %0, %1, %2, %3 neg_lo:[1,0,0] neg_hi:[1,0,0]" : "=v"(d) : "v"(a), "v"(b), "v"(c)); return d;
}
__device__ __forceinline__ f32x2 bc2(float x) { return f32x2{x, x}; }

// complex butterfly: (nr,ni) = (ar+i·ai)·(xr+i·xi) + (br+i·bi)·(yr+i·yi), all elementwise packed
__device__ __forceinline__ void cmad4(f32x2& nr, f32x2& ni,
                                      f32x2 xr, f32x2 xi, f32x2 yr, f32x2 yi,
                                      f32x2 ar, f32x2 ai, f32x2 br, f32x2 bi) {
    f32x2 r = pkmul(ar, xr);
    r = pkfnma(ai, xi, r);
    r = pkfma(br, yr, r);
    r = pkfnma(bi, yi, r);
    f32x2 im = pkmul(ai, xr);
    im = pkfma(ar, xi, im);
    im = pkfma(bi, yr, im);
    im = pkfma(br, yi, im);
    nr = r; ni = im;
}

// ---------------- cross-lane helpers (all VALU, no DS) ----------------
template<int CTRL>
__device__ __forceinline__ f32x2 dpp2(f32x2 v) {
    f32x2 r;
    r.x = __int_as_float(__builtin_amdgcn_update_dpp(__float_as_int(v.x), __float_as_int(v.x), CTRL, 0xF, 0xF, false));
    r.y = __int_as_float(__builtin_amdgcn_update_dpp(__float_as_int(v.y), __float_as_int(v.y), CTRL, 0xF, 0xF, false));
    return r;
}
__device__ __forceinline__ void pswap32(f32x2 v, f32x2& lo, f32x2& hi) {
    float ax = v.x, bx = v.x;
    asm("v_permlane32_swap_b32 %0, %1" : "+v"(ax), "+v"(bx));
    float ay = v.y, by = v.y;
    asm("v_permlane32_swap_b32 %0, %1" : "+v"(ay), "+v"(by));
    lo = f32x2{ax, ay}; hi = f32x2{bx, by};
}
__device__ __forceinline__ void pswap16(f32x2 v, f32x2& ev, f32x2& od) {
    float ax = v.x, bx = v.x;
    asm("v_permlane16_swap_b32 %0, %1" : "+v"(ax), "+v"(bx));
    float ay = v.y, by = v.y;
    asm("v_permlane16_swap_b32 %0, %1" : "+v"(ay), "+v"(by));
    ev = f32x2{ax, ay}; od = f32x2{bx, by};
}
// partner exchange across lane-xor LAM (LAM<32), pure VALU composition
template<unsigned LAM>
__device__ __forceinline__ f32x2 lexch(f32x2 v, int lane) {
    f32x2 r = v;
    if constexpr (LAM & 16u) {
        f32x2 ev, od; pswap16(r, ev, od);
        r = (lane & 16) ? ev : od;       // bit4=1 lanes take the bit4=0 values and vice versa
    }
    if constexpr (LAM & 8u) r = dpp2<0x128>(r);      // row_ror:8 == xor8 within row16
    constexpr unsigned l7 = LAM & 7u;
    if constexpr (l7 == 1) r = dpp2<0xB1>(r);
    else if constexpr (l7 == 2) r = dpp2<0x4E>(r);
    else if constexpr (l7 == 3) r = dpp2<0x1B>(r);
    else if constexpr (l7 == 4) { r = dpp2<0x141>(r); r = dpp2<0x1B>(r); }   // ^7 ^3
    else if constexpr (l7 == 5) { r = dpp2<0x141>(r); r = dpp2<0x4E>(r); }   // ^7 ^2
    else if constexpr (l7 == 6) { r = dpp2<0x141>(r); r = dpp2<0xB1>(r); }   // ^7 ^1
    else if constexpr (l7 == 7) r = dpp2<0x141>(r);
    return r;
}

// ---------------- deferred gate: butterfly with mask m, parity row r ----------------
template<int DI, int J>
__device__ __forceinline__ void deferred_gate(f32x2 rp[4], f32x2 ip[4], const float (*gm)[8],
                                              unsigned xbpos, int lane) {
    constexpr unsigned m = CT.dm[DI][J];
    constexpr unsigned r = CT.dr[DI][J];
    constexpr unsigned lam = m >> 3;
    constexpr unsigned s = m & 7u;
    constexpr int gi = CT.dg[DI][J];
    const float4 ga = *(const float4*)&gm[gi][0];   // u00r,u00i,u01r,u01i
    const float4 gb = *(const float4*)&gm[gi][4];   // u10r,u10i,u11r,u11i
    const int pt = __popc(xbpos & r) & 1;
    // parity class 0: own*u00 + partner*u01 ; class 1: own*u11 + partner*u10
    const float oA_r = pt ? gb.z : ga.x, oA_i = pt ? gb.w : ga.y;   // slot-parity 0
    const float pA_r = pt ? gb.x : ga.z, pA_i = pt ? gb.y : ga.w;
    const float oB_r = pt ? ga.x : gb.z, oB_i = pt ? ga.y : gb.w;   // slot-parity 1
    const float pB_r = pt ? ga.z : gb.x, pB_i = pt ? ga.w : gb.y;
    f32x2 nr[4], ni[4];
    #pragma unroll
    for (int k = 0; k < 4; ++k) {
        const int e0 = __builtin_popcount((unsigned)(2 * k) & (r & 7u)) & 1;
        const int e1 = e0 ^ (int)(r & 1u);
        const int ks = k ^ (int)(s >> 1);
        f32x2 per = lexch<lam>(rp[ks], lane);
        f32x2 pei = lexch<lam>(ip[ks], lane);
        if (s & 1u) { per = f32x2{per.y, per.x}; pei = f32x2{pei.y, pei.x}; }
        const f32x2 oR = f32x2{e0 ? oB_r : oA_r, e1 ? oB_r : oA_r};
        const f32x2 oI = f32x2{e0 ? oB_i : oA_i, e1 ? oB_i : oA_i};
        const f32x2 pR = f32x2{e0 ? pB_r : pA_r, e1 ? pB_r : pA_r};
        const f32x2 pI = f32x2{e0 ? pB_i : pA_i, e1 ? pB_i : pA_i};
        cmad4(nr[k], ni[k], rp[k], ip[k], per, pei, oR, oI, pR, pI);
    }
    #pragma unroll
    for (int k = 0; k < 4; ++k) { rp[k] = nr[k]; ip[k] = ni[k]; }
}

// ---------------- 9 current-layer gates at storage positions 8..0 ----------------
template<int P>
__device__ __forceinline__ void gates9(f32x2 rp[4], f32x2 ip[4], const float (*gm)[8], int lane) {
    { // pos 8: lane bit5 via permlane32_swap (value-indexed coefficient form)
        const float4 ga = *(const float4*)&gm[CT.gq[P][8]][0];
        const float4 gb = *(const float4*)&gm[CT.gq[P][8]][4];
        const int h = (lane >> 5) & 1;
        const f32x2 car = bc2(h ? gb.x : ga.x), cai = bc2(h ? gb.y : ga.y);
        const f32x2 cbr = bc2(h ? gb.z : ga.z), cbi = bc2(h ? gb.w : ga.w);
        #pragma unroll
        for (int k = 0; k < 4; ++k) {
            f32x2 r0r, r1r, r0i, r1i;
            pswap32(rp[k], r0r, r1r);
            pswap32(ip[k], r0i, r1i);
            cmad4(rp[k], ip[k], r0r, r0i, r1r, r1i, car, cai, cbr, cbi);
        }
    }
    { // pos 7: lane bit4 via permlane16_swap
        const float4 ga = *(const float4*)&gm[CT.gq[P][7]][0];
        const float4 gb = *(const float4*)&gm[CT.gq[P][7]][4];
        const int h = (lane >> 4) & 1;
        const f32x2 car = bc2(h ? gb.x : ga.x), cai = bc2(h ? gb.y : ga.y);
        const f32x2 cbr = bc2(h ? gb.z : ga.z), cbi = bc2(h ? gb.w : ga.w);
        #pragma unroll
        for (int k = 0; k < 4; ++k) {
            f32x2 r0r, r1r, r0i, r1i;
            pswap16(rp[k], r0r, r1r);
            pswap16(ip[k], r0i, r1i);
            cmad4(rp[k], ip[k], r0r, r0i, r1r, r1i, car, cai, cbr, cbi);
        }
    }
    { // pos 6: lane bit3 via DPP row_ror:8 (partner form)
        const float4 ga = *(const float4*)&gm[CT.gq[P][6]][0];
        const float4 gb = *(const float4*)&gm[CT.gq[P][6]][4];
        const int h = (lane >> 3) & 1;
        const f32x2 cMer = bc2(h ? gb.z : ga.x), cMei = bc2(h ? gb.w : ga.y);
        const f32x2 cOtr = bc2(h ? gb.x : ga.z), cOti = bc2(h ? gb.y : ga.w);
        #pragma unroll
        for (int k = 0; k < 4; ++k) {
            const f32x2 pR = dpp2<0x128>(rp[k]), pI = dpp2<0x128>(ip[k]);
            cmad4(rp[k], ip[k], rp[k], ip[k], pR, pI, cMer, cMei, cOtr, cOti);
        }
    }
    { // pos 5: lane bit2 via 2-DPP chain (^7 then ^3 = ^4)
        const float4 ga = *(const float4*)&gm[CT.gq[P][5]][0];
        const float4 gb = *(const float4*)&gm[CT.gq[P][5]][4];
        const int h = (lane >> 2) & 1;
        const f32x2 cMer = bc2(h ? gb.z : ga.x), cMei = bc2(h ? gb.w : ga.y);
        const f32x2 cOtr = bc2(h ? gb.x : ga.z), cOti = bc2(h ? gb.y : ga.w);
        #pragma unroll
        for (int k = 0; k < 4; ++k) {
            const f32x2 pR = dpp2<0x1B>(dpp2<0x141>(rp[k]));
            const f32x2 pI = dpp2<0x1B>(dpp2<0x141>(ip[k]));
            cmad4(rp[k], ip[k], rp[k], ip[k], pR, pI, cMer, cMei, cOtr, cOti);
        }
    }
    { // pos 4: lane bit1 via quad_perm ^2
        const float4 ga = *(const float4*)&gm[CT.gq[P][4]][0];
        const float4 gb = *(const float4*)&gm[CT.gq[P][4]][4];
        const int h = (lane >> 1) & 1;
        const f32x2 cMer = bc2(h ? gb.z : ga.x), cMei = bc2(h ? gb.w : ga.y);
        const f32x2 cOtr = bc2(h ? gb.x : ga.z), cOti = bc2(h ? gb.y : ga.w);
        #pragma unroll
        for (int k = 0; k < 4; ++k) {
            const f32x2 pR = dpp2<0x4E>(rp[k]), pI = dpp2<0x4E>(ip[k]);
            cmad4(rp[k], ip[k], rp[k], ip[k], pR, pI, cMer, cMei, cOtr, cOti);
        }
    }
    { // pos 3: lane bit0 via quad_perm ^1
        const float4 ga = *(const float4*)&gm[CT.gq[P][3]][0];
        const float4 gb = *(const float4*)&gm[CT.gq[P][3]][4];
        const int h = lane & 1;
        const f32x2 cMer = bc2(h ? gb.z : ga.x), cMei = bc2(h ? gb.w : ga.y);
        const f32x2 cOtr = bc2(h ? gb.x : ga.z), cOti = bc2(h ? gb.y : ga.w);
        #pragma unroll
        for (int k = 0; k < 4; ++k) {
            const f32x2 pR = dpp2<0xB1>(rp[k]), pI = dpp2<0xB1>(ip[k]);
            cmad4(rp[k], ip[k], rp[k], ip[k], pR, pI, cMer, cMei, cOtr, cOti);
        }
    }
    { // pos 2: reg bit1, pairs (0,2),(1,3)
        const float4 ga = *(const float4*)&gm[CT.gq[P][2]][0];
        const float4 gb = *(const float4*)&gm[CT.gq[P][2]][4];
        const f32x2 g0r = bc2(ga.x), g0i = bc2(ga.y), g1r = bc2(ga.z), g1i = bc2(ga.w);
        const f32x2 h0r = bc2(gb.x), h0i = bc2(gb.y), h1r = bc2(gb.z), h1i = bc2(gb.w);
        #pragma unroll
        for (int h2 = 0; h2 < 2; ++h2) {
            const int k0 = h2, k1 = h2 + 2;
            const f32x2 a0r = rp[k0], a0i = ip[k0], a1r = rp[k1], a1i = ip[k1];
            cmad4(rp[k0], ip[k0], a0r, a0i, a1r, a1i, g0r, g0i, g1r, g1i);
            cmad4(rp[k1], ip[k1], a0r, a0i, a1r, a1i, h0r, h0i, h1r, h1i);
        }
    }
    { // pos 1: reg bit0, pairs (0,1),(2,3)
        const float4 ga = *(const float4*)&gm[CT.gq[P][1]][0];
        const float4 gb = *(const float4*)&gm[CT.gq[P][1]][4];
        const f32x2 g0r = bc2(ga.x), g0i = bc2(ga.y), g1r = bc2(ga.z), g1i = bc2(ga.w);
        const f32x2 h0r = bc2(gb.x), h0i = bc2(gb.y), h1r = bc2(gb.z), h1i = bc2(gb.w);
        #pragma unroll
        for (int h2 = 0; h2 < 2; ++h2) {
            const int k0 = 2 * h2, k1 = k0 + 1;
            const f32x2 a0r = rp[k0], a0i = ip[k0], a1r = rp[k1], a1i = ip[k1];
            cmad4(rp[k0], ip[k0], a0r, a0i, a1r, a1i, g0r, g0i, g1r, g1i);
            cmad4(rp[k1], ip[k1], a0r, a0i, a1r, a1i, h0r, h0i, h1r, h1i);
        }
    }
    { // pos 0: f32x2 component; vector coefficients {row0, row1}
        const float4 ga = *(const float4*)&gm[CT.gq[P][0]][0];
        const float4 gb = *(const float4*)&gm[CT.gq[P][0]][4];
        const f32x2 K0r = f32x2{ga.x, gb.x}, K0i = f32x2{ga.y, gb.y};
        const f32x2 K1r = f32x2{ga.z, gb.z}, K1i = f32x2{ga.w, gb.w};
        #pragma unroll
        for (int k = 0; k < 4; ++k) {
            const f32x2 a0r = bc2(rp[k].x), a0i = bc2(ip[k].x);
            const f32x2 a1r = bc2(rp[k].y), a1i = bc2(ip[k].y);
            cmad4(rp[k], ip[k], a0r, a0i, a1r, a1i, K0r, K0i, K1r, K1i);
        }
    }
}

template<int P>
__device__ __forceinline__ void scatter_p(const f32x2 rp[4], const f32x2 ip[4], float2* wb, int lane, int wv) {
    unsigned sbase = 0;
    #pragma unroll
    for (int j = 0; j < 6; ++j) if ((lane >> j) & 1) sbase ^= CT.lcol[P][j];
    #pragma unroll
    for (int j = 0; j < 3; ++j) if ((wv >> j) & 1) sbase ^= CT.lcol[P][6 + j];
    #pragma unroll
    for (int k = 0; k < 4; ++k) {
        *(float2*)((char*)wb + (sbase ^ CT.scol[P][2 * k]))     = make_float2(rp[k].x, ip[k].x);
        *(float2*)((char*)wb + (sbase ^ CT.scol[P][2 * k + 1])) = make_float2(rp[k].y, ip[k].y);
    }
}

__device__ __forceinline__ void readst(f32x2 rp[4], f32x2 ip[4], const float2* rb, unsigned wbyte) {
    #pragma unroll
    for (int k = 0; k < 4; ++k) {
        const float4 v = *(const float4*)((const char*)rb + (wbyte ^ ((unsigned)k << 4)));
        rp[k] = f32x2{v.x, v.z}; ip[k] = f32x2{v.y, v.w};
    }
}

__global__ __launch_bounds__(NT, 4) void qsim_kernel(
    const float* __restrict__ xin,   // (B,12)
    const float* __restrict__ wts,   // (4,12,3)
    const float* __restrict__ hw,    // (12,)
    const float* __restrict__ hb,    // (1,)
    float* __restrict__ out)         // (B,)
{
    __shared__ alignas(16) float2 buf[2][4096];   // 64 KB double buffer
    __shared__ float gm[NL * NQ][8];
    __shared__ float wred[8];

    const int tid  = threadIdx.x;
    const int lane = tid & 63;
    const int wv   = tid >> 6;
    const int b    = blockIdx.x;
    const int b11 = wv >> 2, b10 = (wv >> 1) & 1, b9 = wv & 1;

    if (tid < NL * NQ) {
        const float phi = wts[tid * 3 + 0];
        const float th  = wts[tid * 3 + 1];
        const float om  = wts[tid * 3 + 2];
        const float ct = cosf(0.5f * th), stt = sinf(0.5f * th);
        const float apo = -0.5f * (phi + om), amo = -0.5f * (phi - om);
        const float epr = cosf(apo), epi = sinf(apo);
        const float emr = cosf(amo), emi = sinf(amo);
        float* g = gm[tid];
        g[0] =  epr * ct;  g[1] =  epi * ct;   // u00
        g[2] = -emr * stt; g[3] =  emi * stt;  // u01
        g[4] =  emr * stt; g[5] =  emi * stt;  // u10
        g[6] =  epr * ct;  g[7] = -epi * ct;   // u11
    }

    // embedding angles (bit bp <-> wire 11-bp)
    float cv[NQ], sv[NQ];
    #pragma unroll
    for (int bp = 0; bp < NQ; ++bp) {
        const float a = 0.5f * xin[b * NQ + (NQ - 1 - bp)];
        cv[bp] = __cosf(a); sv[bp] = __sinf(a);
    }
    float MS[8];
    MS[0] = cv[0]; MS[1] = sv[0];
    #pragma unroll
    for (int bit = 1; bit < 3; ++bit) {
        #pragma unroll
        for (int j = (1 << bit) - 1; j >= 0; --j) {
            MS[j | (1 << bit)] = MS[j] * sv[bit];
            MS[j]              = MS[j] * cv[bit];
        }
    }

    const unsigned xbpos = ((unsigned)wv << 9) | ((unsigned)lane << 3);
    const unsigned wbyte = phi_f(xbpos) << 3;

    __syncthreads();   // gm ready

    f32x2 rp[4], ip[4];

    // ---- phase 0: layer 0 fully in registers (wave wires collapse on product state) ----
    {
        const float* G0 = gm[0];
        const float* G1 = gm[1];
        const float* G2 = gm[2];
        const float w0r = G0[4 * b11] * cv[11]     + G0[4 * b11 + 3] * sv[11];
        const float w0i = G0[4 * b11 + 1] * cv[11] - G0[4 * b11 + 2] * sv[11];
        const float w1r = G1[4 * b10] * cv[10]     + G1[4 * b10 + 3] * sv[10];
        const float w1i = G1[4 * b10 + 1] * cv[10] - G1[4 * b10 + 2] * sv[10];
        const float w2r = G2[4 * b9] * cv[9]       + G2[4 * b9 + 3] * sv[9];
        const float w2i = G2[4 * b9 + 1] * cv[9]   - G2[4 * b9 + 2] * sv[9];
        const float t01r = w0r * w1r - w0i * w1i, t01i = w0r * w1i + w0i * w1r;
        float Ar = t01r * w2r - t01i * w2i;
        float Ai = t01r * w2i + t01i * w2r;
        float mm = 1.f;
        #pragma unroll
        for (int j = 0; j < 6; ++j) mm *= ((lane >> j) & 1) ? sv[3 + j] : cv[3 + j];
        Ar *= mm; Ai *= mm;
        const int pcl = __popc((unsigned)lane) & 3;
        float Br, Bi;
        if      (pcl == 0) { Br =  Ar; Bi =  Ai; }
        else if (pcl == 1) { Br =  Ai; Bi = -Ar; }
        else if (pcl == 2) { Br = -Ar; Bi = -Ai; }
        else               { Br = -Ai; Bi =  Ar; }
        #pragma unroll
        for (int s = 0; s < 8; ++s) {
            const float m = MS[s];
            const int pc = __builtin_popcount((unsigned)s) & 3;
            float ar, ai;
            if      (pc == 0) { ar =  Br * m; ai =  Bi * m; }
            else if (pc == 1) { ar =  Bi * m; ai = -Br * m; }
            else if (pc == 2) { ar = -Br * m; ai = -Bi * m; }
            else              { ar = -Bi * m; ai =  Br * m; }
            if (s & 1) { rp[s >> 1].y = ar; ip[s >> 1].y = ai; }
            else       { rp[s >> 1].x = ar; ip[s >> 1].x = ai; }
        }
        gates9<0>(rp, ip, gm, lane);
        scatter_p<0>(rp, ip, buf[0], lane, wv);
    }
    __syncthreads();

    // ---- phase 1: layer 1 (9 gates), defer D1 ----
    readst(rp, ip, buf[0], wbyte);
    gates9<1>(rp, ip, gm, lane);
    scatter_p<1>(rp, ip, buf[1], lane, wv);
    __syncthreads();

    // ---- phase 2: deferred layer-1 wave gates + layer 2 (9 gates) ----
    readst(rp, ip, buf[1], wbyte);
    deferred_gate<0, 0>(rp, ip, gm, xbpos, lane);
    deferred_gate<0, 1>(rp, ip, gm, xbpos, lane);
    deferred_gate<0, 2>(rp, ip, gm, xbpos, lane);
    gates9<2>(rp, ip, gm, lane);
    scatter_p<2>(rp, ip, buf[0], lane, wv);
    __syncthreads();

    // ---- phase 3: deferred layer-2 + layer 3 (9 gates) ----
    readst(rp, ip, buf[0], wbyte);
    deferred_gate<1, 0>(rp, ip, gm, xbpos, lane);
    deferred_gate<1, 1>(rp, ip, gm, xbpos, lane);
    deferred_gate<1, 2>(rp, ip, gm, xbpos, lane);
    gates9<3>(rp, ip, gm, lane);
    scatter_p<3>(rp, ip, buf[1], lane, wv);
    __syncthreads();

    // ---- phase 4: deferred layer-3 gates + fused <Z_q> + head ----
    {
        readst(rp, ip, buf[1], wbyte);
        deferred_gate<2, 0>(rp, ip, gm, xbpos, lane);
        deferred_gate<2, 1>(rp, ip, gm, xbpos, lane);
        deferred_gate<2, 2>(rp, ip, gm, xbpos, lane);

        float CS[8];
        #pragma unroll
        for (int s = 0; s < 8; ++s) CS[s] = 0.f;
        #pragma unroll
        for (int q = 0; q < NQ; ++q) {
            const unsigned m = CT.rfin[q];
            const float wq = (__popc(xbpos & m) & 1) ? -hw[q] : hw[q];
            #pragma unroll
            for (int s = 0; s < 8; ++s)
                CS[s] += (__builtin_popcount((unsigned)s & m) & 1) ? -wq : wq;
        }
        f32x2 acc = f32x2{0.f, 0.f};
        #pragma unroll
        for (int k = 0; k < 4; ++k) {
            const f32x2 pr = rp[k] * rp[k] + ip[k] * ip[k];
            acc += pr * f32x2{CS[2 * k], CS[2 * k + 1]};
        }
        float sres = acc.x + acc.y;
        #pragma unroll
        for (int off = 32; off >= 1; off >>= 1)
            sres += __shfl_xor(sres, off, 64);
        if (lane == 0) wred[wv] = sres;
        __syncthreads();
        if (tid == 0) {
            float s = hb[0];
            #pragma unroll
            for (int w = 0; w < 8; ++w) s += wred[w];
            out[b] = s;
        }
    }
}

extern "C" void kernel_launch(void* const* d_in, const int* in_sizes, int n_in,
                              void* d_out, int out_size, void* d_ws, size_t ws_size,
                              hipStream_t stream) {
    const float* x  = (const float*)d_in[0];
    const float* wt = (const float*)d_in[1];
    const float* hw = (const float*)d_in[2];
    const float* hb = (const float*)d_in[3];
    float* outp = (float*)d_out;
    const int B = in_sizes[0] / NQ;      // 512
    qsim_kernel<<<B, NT, 0, stream>>>(x, wt, hw, hb, outp);
}

// Round 11
// 31.474 us; speedup vs baseline: 1.0706x; 1.0706x over previous
//
#include <hip/hip_runtime.h>

#define NQ 12
#define NL 4
#define NT 512
// One batch element per block, 8 waves.
// storage position bits: 11,10,9 = wave id (wv bits 2,1,0); 8..3 = lane bits 5..0; 2..0 = slot
// per lane: 8 amps as 4 f32x2 (slot bit0 = f32x2 component)
// Per-phase layout sigma_t maps logical state bits -> storage positions. Gates on the 3
// wave-position bits of layer t are DEFERRED past the ring scatter into phase t+1, where
// (by construction of sigma_{t+1}) their pairing masks are lane/slot-local.
// SINGLE 32KB LDS buffer (read -> barrier -> scatter -> barrier) => 4 blocks/CU, 8 waves/SIMD.

typedef float f32x2 __attribute__((ext_vector_type(2)));

// ---------------- constexpr GF(2) circuit algebra ----------------
constexpr unsigned gmap_f(int l, unsigned v) {      // gather map (verified r1)
    int r = l + 1; unsigned x = v;
    for (int q = NQ - 1; q >= 0; --q) {
        int cb = NQ - 1 - q, tw = (q + r) % NQ, tb = NQ - 1 - tw;
        x ^= ((x >> cb) & 1u) << tb;
    }
    return x;
}
constexpr unsigned ginv_f(int l, unsigned v) {      // scatter map (verified r5)
    int r = l + 1; unsigned x = v;
    for (int q = 0; q < NQ; ++q) {
        int cb = NQ - 1 - q, tw = (q + r) % NQ, tb = NQ - 1 - tw;
        x ^= ((x >> cb) & 1u) << tb;
    }
    return x;
}
constexpr unsigned phi_f(unsigned x) { return x ^ ((x >> 4) & 14u) ^ ((x >> 8) & 14u); }

// sigma_t: logical bit -> storage position (hand-derived; D_t bits at wave positions)
constexpr int POS[5][12] = {
    {0,1,2,3,4,5,6,7,8,9,10,11},        // sigma_0 = identity (phase 0)
    {9,10,11,0,1,2,3,4,5,6,7,8},        // sigma_1: D1={0,1,2}
    {0,1,2,9,5,6,10,7,8,11,3,4},        // sigma_2: D2={3,6,9}
    {0,4,5,1,6,7,2,8,9,3,10,11},        // sigma_3: D3={8,10,11}
    {0,9,2,4,1,10,3,5,11,6,7,8},        // sigma_4: D4={1,5,8}
};
constexpr int DBITS[3][3] = { {0,1,2}, {3,6,9}, {8,10,11} };   // D1,D2,D3

constexpr unsigned pv(int t, unsigned v) { unsigned r = 0; for (int b = 0; b < 12; ++b) if ((v >> b) & 1) r |= 1u << POS[t][b]; return r; }
constexpr int bitat(int t, int i) { for (int b = 0; b < 12; ++b) if (POS[t][b] == i) return b; return -1; }
constexpr unsigned rowmask(int l, int b) { unsigned r = 0; for (int j = 0; j < 12; ++j) if ((gmap_f(l, 1u << j) >> b) & 1) r |= 1u << j; return r; }

struct Tabs {
    unsigned lcol[4][9];    // scatter phases 0..3: byte cols for position bits 3..11
    unsigned scol[4][8];    // scatter byte combos over slot bits 0..2
    int      gq[4][9];      // current-gate matrix index at position i (phases 0..3)
    unsigned dm[3][3];      // deferred masks (applied in phases 2,3,4)
    unsigned dr[3][3];      // deferred parity rows (storage space)
    int      dg[3][3];      // deferred gate matrix index
    unsigned rfin[12];      // measurement masks (single storage bits)
};
constexpr Tabs make_tabs() {
    Tabs T{};
    for (int t = 0; t <= 3; ++t) {
        for (int i = 3; i < 12; ++i)
            T.lcol[t][i - 3] = phi_f(pv(t + 1, ginv_f(t, 1u << bitat(t, i)))) << 3;
        for (int s = 0; s < 8; ++s) {
            unsigned v = 0;
            for (int bp = 0; bp < 3; ++bp)
                if ((s >> bp) & 1) v ^= phi_f(pv(t + 1, ginv_f(t, 1u << bitat(t, bp)))) << 3;
            T.scol[t][s] = v;
        }
        for (int i = 0; i < 9; ++i)
            T.gq[t][i] = t * NQ + (11 - bitat(t, i));
    }
    for (int t = 2; t <= 4; ++t)
        for (int j = 0; j < 3; ++j) {
            const int b = DBITS[t - 2][j];
            T.dm[t - 2][j] = pv(t, ginv_f(t - 1, 1u << b));
            T.dr[t - 2][j] = pv(t, rowmask(t - 1, b));
            T.dg[t - 2][j] = (t - 1) * NQ + (11 - b);
        }
    for (int q = 0; q < 12; ++q) T.rfin[q] = 1u << POS[4][11 - q];
    return T;
}
constexpr Tabs CT = make_tabs();

constexpr bool chk() {
    for (int t = 1; t <= 4; ++t) { unsigned seen = 0; for (int b = 0; b < 12; ++b) seen |= 1u << POS[t][b]; if (seen != 0xFFFu) return false; }
    for (int t = 1; t <= 3; ++t)
        for (int j = 0; j < 3; ++j) {
            if (POS[t][DBITS[t - 1][j]] < 9) return false;                 // D_t at wave under sigma_t
            if (pv(t + 1, ginv_f(t, 1u << DBITS[t - 1][j])) >> 9) return false; // deferred mask lane/slot
        }
    for (int j = 0; j < 3; ++j) if ((CT.dm[0][j] >> 3) > 31 || (CT.dm[1][j] >> 3) > 31 || (CT.dm[2][j] >> 3) > 31) return false;
    return true;
}
static_assert(chk(), "layout constraints violated");

// ---------------- cross-lane helpers (all VALU, no DS) ----------------
template<int CTRL>
__device__ __forceinline__ f32x2 dpp2(f32x2 v) {
    f32x2 r;
    r.x = __int_as_float(__builtin_amdgcn_update_dpp(__float_as_int(v.x), __float_as_int(v.x), CTRL, 0xF, 0xF, false));
    r.y = __int_as_float(__builtin_amdgcn_update_dpp(__float_as_int(v.y), __float_as_int(v.y), CTRL, 0xF, 0xF, false));
    return r;
}
__device__ __forceinline__ void pswap32(f32x2 v, f32x2& lo, f32x2& hi) {
    float ax = v.x, bx = v.x;
    asm("v_permlane32_swap_b32 %0, %1" : "+v"(ax), "+v"(bx));
    float ay = v.y, by = v.y;
    asm("v_permlane32_swap_b32 %0, %1" : "+v"(ay), "+v"(by));
    lo = f32x2{ax, ay}; hi = f32x2{bx, by};
}
__device__ __forceinline__ void pswap16(f32x2 v, f32x2& ev, f32x2& od) {
    float ax = v.x, bx = v.x;
    asm("v_permlane16_swap_b32 %0, %1" : "+v"(ax), "+v"(bx));
    float ay = v.y, by = v.y;
    asm("v_permlane16_swap_b32 %0, %1" : "+v"(ay), "+v"(by));
    ev = f32x2{ax, ay}; od = f32x2{bx, by};
}
// partner exchange across lane-xor LAM (LAM<32), pure VALU composition
template<unsigned LAM>
__device__ __forceinline__ f32x2 lexch(f32x2 v, int lane) {
    f32x2 r = v;
    if constexpr (LAM & 16u) {
        f32x2 ev, od; pswap16(r, ev, od);
        r = (lane & 16) ? ev : od;       // bit4=1 lanes take the bit4=0 values and vice versa
    }
    if constexpr (LAM & 8u) r = dpp2<0x128>(r);      // row_ror:8 == xor8 within row16
    constexpr unsigned l7 = LAM & 7u;
    if constexpr (l7 == 1) r = dpp2<0xB1>(r);
    else if constexpr (l7 == 2) r = dpp2<0x4E>(r);
    else if constexpr (l7 == 3) r = dpp2<0x1B>(r);
    else if constexpr (l7 == 4) { r = dpp2<0x141>(r); r = dpp2<0x1B>(r); }   // ^7 ^3
    else if constexpr (l7 == 5) { r = dpp2<0x141>(r); r = dpp2<0x4E>(r); }   // ^7 ^2
    else if constexpr (l7 == 6) { r = dpp2<0x141>(r); r = dpp2<0xB1>(r); }   // ^7 ^1
    else if constexpr (l7 == 7) r = dpp2<0x141>(r);
    return r;
}

// ---------------- deferred gate: butterfly with mask m, parity row r ----------------
template<int DI, int J>
__device__ __forceinline__ void deferred_gate(f32x2 rp[4], f32x2 ip[4], const float (*gm)[8],
                                              unsigned xbpos, int lane) {
    constexpr unsigned m = CT.dm[DI][J];
    constexpr unsigned r = CT.dr[DI][J];
    constexpr unsigned lam = m >> 3;
    constexpr unsigned s = m & 7u;
    constexpr int gi = CT.dg[DI][J];
    const float4 ga = *(const float4*)&gm[gi][0];   // u00r,u00i,u01r,u01i
    const float4 gb = *(const float4*)&gm[gi][4];   // u10r,u10i,u11r,u11i
    const int pt = __popc(xbpos & r) & 1;
    // parity class 0: own*u00 + partner*u01 ; class 1: own*u11 + partner*u10
    const float oA_r = pt ? gb.z : ga.x, oA_i = pt ? gb.w : ga.y;   // slot-parity 0
    const float pA_r = pt ? gb.x : ga.z, pA_i = pt ? gb.y : ga.w;
    const float oB_r = pt ? ga.x : gb.z, oB_i = pt ? ga.y : gb.w;   // slot-parity 1
    const float pB_r = pt ? ga.z : gb.x, pB_i = pt ? ga.w : gb.y;
    f32x2 nr[4], ni[4];
    #pragma unroll
    for (int k = 0; k < 4; ++k) {
        const int e0 = __builtin_popcount((unsigned)(2 * k) & (r & 7u)) & 1;
        const int e1 = e0 ^ (int)(r & 1u);
        const int ks = k ^ (int)(s >> 1);
        f32x2 per = lexch<lam>(rp[ks], lane);
        f32x2 pei = lexch<lam>(ip[ks], lane);
        if (s & 1u) { per = f32x2{per.y, per.x}; pei = f32x2{pei.y, pei.x}; }
        const f32x2 oR = f32x2{e0 ? oB_r : oA_r, e1 ? oB_r : oA_r};
        const f32x2 oI = f32x2{e0 ? oB_i : oA_i, e1 ? oB_i : oA_i};
        const f32x2 pR = f32x2{e0 ? pB_r : pA_r, e1 ? pB_r : pA_r};
        const f32x2 pI = f32x2{e0 ? pB_i : pA_i, e1 ? pB_i : pA_i};
        nr[k] = oR * rp[k] - oI * ip[k] + pR * per - pI * pei;
        ni[k] = oI * rp[k] + oR * ip[k] + pI * per + pR * pei;
    }
    #pragma unroll
    for (int k = 0; k < 4; ++k) { rp[k] = nr[k]; ip[k] = ni[k]; }
}

// ---------------- 9 current-layer gates at storage positions 8..0 ----------------
template<int P>
__device__ __forceinline__ void gates9(f32x2 rp[4], f32x2 ip[4], const float (*gm)[8], int lane) {
    { // pos 8: lane bit5 via permlane32_swap (value-indexed coefficient form)
        const float4 ga = *(const float4*)&gm[CT.gq[P][8]][0];
        const float4 gb = *(const float4*)&gm[CT.gq[P][8]][4];
        const int h = (lane >> 5) & 1;
        const float car = h ? gb.x : ga.x, cai = h ? gb.y : ga.y;
        const float cbr = h ? gb.z : ga.z, cbi = h ? gb.w : ga.w;
        #pragma unroll
        for (int k = 0; k < 4; ++k) {
            f32x2 r0r, r1r, r0i, r1i;
            pswap32(rp[k], r0r, r1r);
            pswap32(ip[k], r0i, r1i);
            rp[k] = car * r0r - cai * r0i + cbr * r1r - cbi * r1i;
            ip[k] = cai * r0r + car * r0i + cbi * r1r + cbr * r1i;
        }
    }
    { // pos 7: lane bit4 via permlane16_swap
        const float4 ga = *(const float4*)&gm[CT.gq[P][7]][0];
        const float4 gb = *(const float4*)&gm[CT.gq[P][7]][4];
        const int h = (lane >> 4) & 1;
        const float car = h ? gb.x : ga.x, cai = h ? gb.y : ga.y;
        const float cbr = h ? gb.z : ga.z, cbi = h ? gb.w : ga.w;
        #pragma unroll
        for (int k = 0; k < 4; ++k) {
            f32x2 r0r, r1r, r0i, r1i;
            pswap16(rp[k], r0r, r1r);
            pswap16(ip[k], r0i, r1i);
            rp[k] = car * r0r - cai * r0i + cbr * r1r - cbi * r1i;
            ip[k] = cai * r0r + car * r0i + cbi * r1r + cbr * r1i;
        }
    }
    { // pos 6: lane bit3 via DPP row_ror:8 (partner form)
        const float4 ga = *(const float4*)&gm[CT.gq[P][6]][0];
        const float4 gb = *(const float4*)&gm[CT.gq[P][6]][4];
        const int h = (lane >> 3) & 1;
        const float cMer = h ? gb.z : ga.x, cMei = h ? gb.w : ga.y;
        const float cOtr = h ? gb.x : ga.z, cOti = h ? gb.y : ga.w;
        #pragma unroll
        for (int k = 0; k < 4; ++k) {
            const f32x2 pR = dpp2<0x128>(rp[k]), pI = dpp2<0x128>(ip[k]);
            const f32x2 nr = cMer * rp[k] - cMei * ip[k] + cOtr * pR - cOti * pI;
            const f32x2 ni = cMei * rp[k] + cMer * ip[k] + cOti * pR + cOtr * pI;
            rp[k] = nr; ip[k] = ni;
        }
    }
    { // pos 5: lane bit2 via 2-DPP chain (^7 then ^3 = ^4)
        const float4 ga = *(const float4*)&gm[CT.gq[P][5]][0];
        const float4 gb = *(const float4*)&gm[CT.gq[P][5]][4];
        const int h = (lane >> 2) & 1;
        const float cMer = h ? gb.z : ga.x, cMei = h ? gb.w : ga.y;
        const float cOtr = h ? gb.x : ga.z, cOti = h ? gb.y : ga.w;
        #pragma unroll
        for (int k = 0; k < 4; ++k) {
            const f32x2 pR = dpp2<0x1B>(dpp2<0x141>(rp[k]));
            const f32x2 pI = dpp2<0x1B>(dpp2<0x141>(ip[k]));
            const f32x2 nr = cMer * rp[k] - cMei * ip[k] + cOtr * pR - cOti * pI;
            const f32x2 ni = cMei * rp[k] + cMer * ip[k] + cOti * pR + cOtr * pI;
            rp[k] = nr; ip[k] = ni;
        }
    }
    { // pos 4: lane bit1 via quad_perm ^2
        const float4 ga = *(const float4*)&gm[CT.gq[P][4]][0];
        const float4 gb = *(const float4*)&gm[CT.gq[P][4]][4];
        const int h = (lane >> 1) & 1;
        const float cMer = h ? gb.z : ga.x, cMei = h ? gb.w : ga.y;
        const float cOtr = h ? gb.x : ga.z, cOti = h ? gb.y : ga.w;
        #pragma unroll
        for (int k = 0; k < 4; ++k) {
            const f32x2 pR = dpp2<0x4E>(rp[k]), pI = dpp2<0x4E>(ip[k]);
            const f32x2 nr = cMer * rp[k] - cMei * ip[k] + cOtr * pR - cOti * pI;
            const f32x2 ni = cMei * rp[k] + cMer * ip[k] + cOti * pR + cOtr * pI;
            rp[k] = nr; ip[k] = ni;
        }
    }
    { // pos 3: lane bit0 via quad_perm ^1
        const float4 ga = *(const float4*)&gm[CT.gq[P][3]][0];
        const float4 gb = *(const float4*)&gm[CT.gq[P][3]][4];
        const int h = lane & 1;
        const float cMer = h ? gb.z : ga.x, cMei = h ? gb.w : ga.y;
        const float cOtr = h ? gb.x : ga.z, cOti = h ? gb.y : ga.w;
        #pragma unroll
        for (int k = 0; k < 4; ++k) {
            const f32x2 pR = dpp2<0xB1>(rp[k]), pI = dpp2<0xB1>(ip[k]);
            const f32x2 nr = cMer * rp[k] - cMei * ip[k] + cOtr * pR - cOti * pI;
            const f32x2 ni = cMei * rp[k] + cMer * ip[k] + cOti * pR + cOtr * pI;
            rp[k] = nr; ip[k] = ni;
        }
    }
    { // pos 2: reg bit1, pairs (0,2),(1,3)
        const float4 ga = *(const float4*)&gm[CT.gq[P][2]][0];
        const float4 gb = *(const float4*)&gm[CT.gq[P][2]][4];
        #pragma unroll
        for (int h2 = 0; h2 < 2; ++h2) {
            const int k0 = h2, k1 = h2 + 2;
            const f32x2 a0r = rp[k0], a0i = ip[k0], a1r = rp[k1], a1i = ip[k1];
            rp[k0] = ga.x * a0r - ga.y * a0i + ga.z * a1r - ga.w * a1i;
            ip[k0] = ga.y * a0r + ga.x * a0i + ga.w * a1r + ga.z * a1i;
            rp[k1] = gb.x * a0r - gb.y * a0i + gb.z * a1r - gb.w * a1i;
            ip[k1] = gb.y * a0r + gb.x * a0i + gb.w * a1r + gb.z * a1i;
        }
    }
    { // pos 1: reg bit0, pairs (0,1),(2,3)
        const float4 ga = *(const float4*)&gm[CT.gq[P][1]][0];
        const float4 gb = *(const float4*)&gm[CT.gq[P][1]][4];
        #pragma unroll
        for (int h2 = 0; h2 < 2; ++h2) {
            const int k0 = 2 * h2, k1 = k0 + 1;
            const f32x2 a0r = rp[k0], a0i = ip[k0], a1r = rp[k1], a1i = ip[k1];
            rp[k0] = ga.x * a0r - ga.y * a0i + ga.z * a1r - ga.w * a1i;
            ip[k0] = ga.y * a0r + ga.x * a0i + ga.w * a1r + ga.z * a1i;
            rp[k1] = gb.x * a0r - gb.y * a0i + gb.z * a1r - gb.w * a1i;
            ip[k1] = gb.y * a0r + gb.x * a0i + gb.w * a1r + gb.z * a1i;
        }
    }
    { // pos 0: f32x2 component, coefficient pairs {row0,row1}
        const float4 ga = *(const float4*)&gm[CT.gq[P][0]][0];
        const float4 gb = *(const float4*)&gm[CT.gq[P][0]][4];
        const f32x2 K0r = f32x2{ga.x, gb.x}, K0i = f32x2{ga.y, gb.y};
        const f32x2 K1r = f32x2{ga.z, gb.z}, K1i = f32x2{ga.w, gb.w};
        #pragma unroll
        for (int k = 0; k < 4; ++k) {
            const float a0r = rp[k].x, a0i = ip[k].x, a1r = rp[k].y, a1i = ip[k].y;
            rp[k] = K0r * a0r - K0i * a0i + K1r * a1r - K1i * a1i;
            ip[k] = K0i * a0r + K0r * a0i + K1i * a1r + K1r * a1i;
        }
    }
}

template<int P>
__device__ __forceinline__ void scatter_p(const f32x2 rp[4], const f32x2 ip[4], float2* wb, int lane, int wv) {
    unsigned sbase = 0;
    #pragma unroll
    for (int j = 0; j < 6; ++j) if ((lane >> j) & 1) sbase ^= CT.lcol[P][j];
    #pragma unroll
    for (int j = 0; j < 3; ++j) if ((wv >> j) & 1) sbase ^= CT.lcol[P][6 + j];
    #pragma unroll
    for (int k = 0; k < 4; ++k) {
        *(float2*)((char*)wb + (sbase ^ CT.scol[P][2 * k]))     = make_float2(rp[k].x, ip[k].x);
        *(float2*)((char*)wb + (sbase ^ CT.scol[P][2 * k + 1])) = make_float2(rp[k].y, ip[k].y);
    }
}

__device__ __forceinline__ void readst(f32x2 rp[4], f32x2 ip[4], const float2* rb, unsigned wbyte) {
    #pragma unroll
    for (int k = 0; k < 4; ++k) {
        const float4 v = *(const float4*)((const char*)rb + (wbyte ^ ((unsigned)k << 4)));
        rp[k] = f32x2{v.x, v.z}; ip[k] = f32x2{v.y, v.w};
    }
}

__global__ __launch_bounds__(NT, 8) void qsim_kernel(
    const float* __restrict__ xin,   // (B,12)
    const float* __restrict__ wts,   // (4,12,3)
    const float* __restrict__ hw,    // (12,)
    const float* __restrict__ hb,    // (1,)
    float* __restrict__ out)         // (B,)
{
    __shared__ alignas(16) float2 buf[4096];      // 32 KB single buffer -> 4 blocks/CU
    __shared__ float gm[NL * NQ][8];
    __shared__ float wred[8];

    const int tid  = threadIdx.x;
    const int lane = tid & 63;
    const int wv   = tid >> 6;
    const int b    = blockIdx.x;
    const int b11 = wv >> 2, b10 = (wv >> 1) & 1, b9 = wv & 1;

    if (tid < NL * NQ) {
        const float phi = wts[tid * 3 + 0];
        const float th  = wts[tid * 3 + 1];
        const float om  = wts[tid * 3 + 2];
        const float ct = cosf(0.5f * th), stt = sinf(0.5f * th);
        const float apo = -0.5f * (phi + om), amo = -0.5f * (phi - om);
        const float epr = cosf(apo), epi = sinf(apo);
        const float emr = cosf(amo), emi = sinf(amo);
        float* g = gm[tid];
        g[0] =  epr * ct;  g[1] =  epi * ct;   // u00
        g[2] = -emr * stt; g[3] =  emi * stt;  // u01
        g[4] =  emr * stt; g[5] =  emi * stt;  // u10
        g[6] =  epr * ct;  g[7] = -epi * ct;   // u11
    }

    // embedding angles (bit bp <-> wire 11-bp)
    float cv[NQ], sv[NQ];
    #pragma unroll
    for (int bp = 0; bp < NQ; ++bp) {
        const float a = 0.5f * xin[b * NQ + (NQ - 1 - bp)];
        cv[bp] = __cosf(a); sv[bp] = __sinf(a);
    }
    float MS[8];
    MS[0] = cv[0]; MS[1] = sv[0];
    #pragma unroll
    for (int bit = 1; bit < 3; ++bit) {
        #pragma unroll
        for (int j = (1 << bit) - 1; j >= 0; --j) {
            MS[j | (1 << bit)] = MS[j] * sv[bit];
            MS[j]              = MS[j] * cv[bit];
        }
    }

    const unsigned xbpos = ((unsigned)wv << 9) | ((unsigned)lane << 3);
    const unsigned wbyte = phi_f(xbpos) << 3;

    __syncthreads();   // gm ready

    f32x2 rp[4], ip[4];

    // ---- phase 0: layer 0 fully in registers (wave wires collapse on product state) ----
    {
        const float* G0 = gm[0];
        const float* G1 = gm[1];
        const float* G2 = gm[2];
        const float w0r = G0[4 * b11] * cv[11]     + G0[4 * b11 + 3] * sv[11];
        const float w0i = G0[4 * b11 + 1] * cv[11] - G0[4 * b11 + 2] * sv[11];
        const float w1r = G1[4 * b10] * cv[10]     + G1[4 * b10 + 3] * sv[10];
        const float w1i = G1[4 * b10 + 1] * cv[10] - G1[4 * b10 + 2] * sv[10];
        const float w2r = G2[4 * b9] * cv[9]       + G2[4 * b9 + 3] * sv[9];
        const float w2i = G2[4 * b9 + 1] * cv[9]   - G2[4 * b9 + 2] * sv[9];
        const float t01r = w0r * w1r - w0i * w1i, t01i = w0r * w1i + w0i * w1r;
        float Ar = t01r * w2r - t01i * w2i;
        float Ai = t01r * w2i + t01i * w2r;
        float mm = 1.f;
        #pragma unroll
        for (int j = 0; j < 6; ++j) mm *= ((lane >> j) & 1) ? sv[3 + j] : cv[3 + j];
        Ar *= mm; Ai *= mm;
        const int pcl = __popc((unsigned)lane) & 3;
        float Br, Bi;
        if      (pcl == 0) { Br =  Ar; Bi =  Ai; }
        else if (pcl == 1) { Br =  Ai; Bi = -Ar; }
        else if (pcl == 2) { Br = -Ar; Bi = -Ai; }
        else               { Br = -Ai; Bi =  Ar; }
        #pragma unroll
        for (int s = 0; s < 8; ++s) {
            const float m = MS[s];
            const int pc = __builtin_popcount((unsigned)s) & 3;
            float ar, ai;
            if      (pc == 0) { ar =  Br * m; ai =  Bi * m; }
            else if (pc == 1) { ar =  Bi * m; ai = -Br * m; }
            else if (pc == 2) { ar = -Br * m; ai = -Bi * m; }
            else              { ar = -Bi * m; ai =  Br * m; }
            if (s & 1) { rp[s >> 1].y = ar; ip[s >> 1].y = ai; }
            else       { rp[s >> 1].x = ar; ip[s >> 1].x = ai; }
        }
        gates9<0>(rp, ip, gm, lane);
        scatter_p<0>(rp, ip, buf, lane, wv);
    }
    __syncthreads();

    // ---- phase 1: layer 1 (9 gates), defer D1 ----
    readst(rp, ip, buf, wbyte);
    gates9<1>(rp, ip, gm, lane);
    __syncthreads();                    // all reads done before overwrite
    scatter_p<1>(rp, ip, buf, lane, wv);
    __syncthreads();

    // ---- phase 2: deferred layer-1 wave gates + layer 2 (9 gates) ----
    readst(rp, ip, buf, wbyte);
    deferred_gate<0, 0>(rp, ip, gm, xbpos, lane);
    deferred_gate<0, 1>(rp, ip, gm, xbpos, lane);
    deferred_gate<0, 2>(rp, ip, gm, xbpos, lane);
    gates9<2>(rp, ip, gm, lane);
    __syncthreads();
    scatter_p<2>(rp, ip, buf, lane, wv);
    __syncthreads();

    // ---- phase 3: deferred layer-2 + layer 3 (9 gates) ----
    readst(rp, ip, buf, wbyte);
    deferred_gate<1, 0>(rp, ip, gm, xbpos, lane);
    deferred_gate<1, 1>(rp, ip, gm, xbpos, lane);
    deferred_gate<1, 2>(rp, ip, gm, xbpos, lane);
    gates9<3>(rp, ip, gm, lane);
    __syncthreads();
    scatter_p<3>(rp, ip, buf, lane, wv);
    __syncthreads();

    // ---- phase 4: deferred layer-3 gates + fused <Z_q> + head ----
    {
        readst(rp, ip, buf, wbyte);
        deferred_gate<2, 0>(rp, ip, gm, xbpos, lane);
        deferred_gate<2, 1>(rp, ip, gm, xbpos, lane);
        deferred_gate<2, 2>(rp, ip, gm, xbpos, lane);

        float CS[8];
        #pragma unroll
        for (int s = 0; s < 8; ++s) CS[s] = 0.f;
        #pragma unroll
        for (int q = 0; q < NQ; ++q) {
            const unsigned m = CT.rfin[q];
            const float wq = (__popc(xbpos & m) & 1) ? -hw[q] : hw[q];
            #pragma unroll
            for (int s = 0; s < 8; ++s)
                CS[s] += (__builtin_popcount((unsigned)s & m) & 1) ? -wq : wq;
        }
        f32x2 acc = f32x2{0.f, 0.f};
        #pragma unroll
        for (int k = 0; k < 4; ++k) {
            const f32x2 pr = rp[k] * rp[k] + ip[k] * ip[k];
            acc += pr * f32x2{CS[2 * k], CS[2 * k + 1]};
        }
        float sres = acc.x + acc.y;
        #pragma unroll
        for (int off = 32; off >= 1; off >>= 1)
            sres += __shfl_xor(sres, off, 64);
        if (lane == 0) wred[wv] = sres;
        __syncthreads();
        if (tid == 0) {
            float s = hb[0];
            #pragma unroll
            for (int w = 0; w < 8; ++w) s += wred[w];
            out[b] = s;
        }
    }
}

extern "C" void kernel_launch(void* const* d_in, const int* in_sizes, int n_in,
                              void* d_out, int out_size, void* d_ws, size_t ws_size,
                              hipStream_t stream) {
    const float* x  = (const float*)d_in[0];
    const float* wt = (const float*)d_in[1];
    const float* hw = (const float*)d_in[2];
    const float* hb = (const float*)d_in[3];
    float* outp = (float*)d_out;
    const int B = in_sizes[0] / NQ;      // 512
    qsim_kernel<<<B, NT, 0, stream>>>(x, wt, hw, hb, outp);
}